// Round 1
// baseline (1413.883 us; speedup 1.0000x reference)
//
#include <hip/hip_runtime.h>
#include <math.h>

#define BN 16
#define CN 256
#define HN 224
#define WN 224
#define HW (HN*WN)            // 50176
#define PLANES (BN*CN)        // 4096
#define F4_PER_PLANE (HW/4)   // 12544
#define F4_PER_ROW (WN/4)     // 56

// ---------------- Kernel 1: per-plane parity-class sums ----------------
// sums[plane*4 + j], j = rowpar*2 + colpar:
//   0 = even row, even col (x1) ; 1 = even row, odd col (x3)
//   2 = odd  row, even col (x2) ; 3 = odd  row, odd col (x4)
__global__ __launch_bounds__(256) void reduce_kernel(const float* __restrict__ x,
                                                     float* __restrict__ sums) {
    const int plane = blockIdx.x;
    const float4* xv = (const float4*)(x + (size_t)plane * HW);
    const int tid = threadIdx.x;

    float a00 = 0.f, a01 = 0.f, a10 = 0.f, a11 = 0.f;
    for (int i = tid; i < F4_PER_PLANE; i += 256) {
        const int h = i / F4_PER_ROW;       // magic-mul division
        float4 v = xv[i];
        float e = v.x + v.z;                // even columns (w%2==0)
        float o = v.y + v.w;                // odd columns
        if (h & 1) { a10 += e; a11 += o; }
        else       { a00 += e; a01 += o; }
    }

    float a[4] = {a00, a01, a10, a11};
    #pragma unroll
    for (int j = 0; j < 4; ++j)
        #pragma unroll
        for (int off = 32; off > 0; off >>= 1)
            a[j] += __shfl_down(a[j], off);

    __shared__ float red[4][4];
    const int wave = tid >> 6, lane = tid & 63;
    if (lane == 0) {
        red[wave][0] = a[0]; red[wave][1] = a[1];
        red[wave][2] = a[2]; red[wave][3] = a[3];
    }
    __syncthreads();
    if (tid < 4) {
        sums[plane * 4 + tid] = red[0][tid] + red[1][tid] + red[2][tid] + red[3][tid];
    }
}

// ---------------- Kernel 2: gating math, one block per batch ----------------
__global__ __launch_bounds__(256) void middle_kernel(const float* __restrict__ sums,
                                                     const float* __restrict__ w1,
                                                     const float* __restrict__ w2,
                                                     const float* __restrict__ w_enc,
                                                     const float* __restrict__ b_enc,
                                                     float* __restrict__ s_out) {
    const int b = blockIdx.x;
    const int c = threadIdx.x;   // 0..255 == channel

    __shared__ float oy[4][CN];
    __shared__ float red[4][4];
    __shared__ float yld[CN];
    __shared__ float hld[CN / 2];
    __shared__ int top_s;

    const float scale = 0.5f / (112.0f * 112.0f);
    const float S1 = sums[(b * CN + c) * 4 + 0];   // even row, even col
    const float S3 = sums[(b * CN + c) * 4 + 1];   // even row, odd col
    const float S2 = sums[(b * CN + c) * 4 + 2];   // odd row,  even col
    const float S4 = sums[(b * CN + c) * 4 + 3];   // odd row,  odd col

    const float LL = ( S1 + S2 + S3 + S4) * scale;
    const float HL = (-S1 - S2 + S3 + S4) * scale;
    const float LH = (-S1 + S2 - S3 + S4) * scale;
    const float HH = ( S1 - S2 - S3 + S4) * scale;
    oy[0][c] = LL; oy[1][c] = HL; oy[2][c] = LH; oy[3][c] = HH;

    // dot(ori_y[b,k,:], w_enc) via shuffle reduce
    const float we = w_enc[c];
    float p[4] = {LL * we, HL * we, LH * we, HH * we};
    #pragma unroll
    for (int j = 0; j < 4; ++j)
        #pragma unroll
        for (int off = 32; off > 0; off >>= 1)
            p[j] += __shfl_down(p[j], off);
    const int wave = c >> 6, lane = c & 63;
    if (lane == 0) {
        red[wave][0] = p[0]; red[wave][1] = p[1];
        red[wave][2] = p[2]; red[wave][3] = p[3];
    }
    __syncthreads();
    if (c == 0) {
        float best = -1e30f; int bi = 0;
        for (int k = 0; k < 4; ++k) {
            float d = red[0][k] + red[1][k] + red[2][k] + red[3][k] + b_enc[0];
            float a1 = 1.0f / (1.0f + expf(-d));     // monotonic; first-max tie rule
            if (a1 > best) { best = a1; bi = k; }
        }
        top_s = bi;
    }
    __syncthreads();

    const int top = top_s;
    const float q = oy[top][c];
    const float y = fmaxf(oy[0][c] - q, 0.f) + fmaxf(oy[1][c] - q, 0.f) +
                    fmaxf(oy[2][c] - q, 0.f) + fmaxf(oy[3][c] - q, 0.f);
    yld[c] = y;
    __syncthreads();

    if (c < 128) {                        // h = relu(y @ w1^T), w1 is (128,256)
        float acc = 0.f;
        const float* wr = w1 + c * CN;
        #pragma unroll 8
        for (int k = 0; k < CN; ++k) acc += yld[k] * wr[k];
        hld[c] = fmaxf(acc, 0.f);
    }
    __syncthreads();

    {                                     // s = sigmoid(h @ w2^T), w2 is (256,128)
        float acc = 0.f;
        const float* wr = w2 + c * 128;
        #pragma unroll 8
        for (int k = 0; k < 128; ++k) acc += hld[k] * wr[k];
        s_out[b * CN + c] = 1.0f / (1.0f + expf(-acc));
    }
}

// ---------------- Kernel 3: out = x * s[plane] ----------------
__global__ __launch_bounds__(256) void scale_kernel(const float* __restrict__ x,
                                                    const float* __restrict__ s,
                                                    float* __restrict__ out) {
    const int plane = blockIdx.y;
    const float sv = s[plane];
    const size_t base = (size_t)plane * F4_PER_PLANE;
    const size_t i = base + blockIdx.x * 256 + threadIdx.x;   // 49*256 == 12544 exactly
    const float4* xv = (const float4*)x;
    float4* ov = (float4*)out;
    float4 v = xv[i];
    v.x *= sv; v.y *= sv; v.z *= sv; v.w *= sv;
    ov[i] = v;
}

extern "C" void kernel_launch(void* const* d_in, const int* in_sizes, int n_in,
                              void* d_out, int out_size, void* d_ws, size_t ws_size,
                              hipStream_t stream) {
    const float* x     = (const float*)d_in[0];
    const float* w1    = (const float*)d_in[1];
    const float* w2    = (const float*)d_in[2];
    const float* w_enc = (const float*)d_in[3];
    const float* b_enc = (const float*)d_in[4];
    float* out = (float*)d_out;

    float* sums = (float*)d_ws;            // PLANES*4 floats
    float* s    = sums + PLANES * 4;       // PLANES floats

    reduce_kernel<<<PLANES, 256, 0, stream>>>(x, sums);
    middle_kernel<<<BN, 256, 0, stream>>>(sums, w1, w2, w_enc, b_enc, s);
    scale_kernel<<<dim3(49, PLANES), 256, 0, stream>>>(x, s, out);
}